// Round 6
// baseline (276.342 us; speedup 1.0000x reference)
//
#include <hip/hip_runtime.h>

// Mamba-2 SSD chunked scan. b=4, s=8192, h=32, p=64, n=16, l=64, c=128.
// k1: one block per chunk -> local state S_c (MFMA) + alast_c. Fully parallel.
// k2: per-chain 128-step scan over states, in place -> incoming prefix P_c.
// k3: one block per chunk -> Y, async-pipelined staging, MFMA.
#define BB 4
#define SS 8192
#define HH 32
#define PP 64
#define NN 16
#define LL 64
#define CC 128
#define NCHAIN (BB * HH)         // 128 chains
#define NCHT (NCHAIN * CC)       // 16384 chunks

typedef __attribute__((ext_vector_type(8))) short bf16x8;
typedef __attribute__((ext_vector_type(4))) short bf16x4;
typedef __attribute__((ext_vector_type(4))) float f32x4;

__device__ inline short f2bf(float f) {
    unsigned u = __builtin_bit_cast(unsigned, f);
    u = (u + 0x7FFFu + ((u >> 16) & 1u)) >> 16;
    return (short)u;
}

// ---------------------------------------------------------------------------
// K1: per chunk local state S_c[p][n] = sum_l B[l][n]*exp(alast-cs_l)*X[l][p].
// ---------------------------------------------------------------------------
__global__ __launch_bounds__(256) void k1_states(
    const float* __restrict__ X, const float* __restrict__ A,
    const float* __restrict__ B, float* __restrict__ states,
    float* __restrict__ alast_g)
{
    int blk = blockIdx.x;
    int h = blk & (HH - 1);
    int c = (blk >> 5) & (CC - 1);
    int b = blk >> 12;
    int tid = threadIdx.x;
    int w = tid >> 6, l = tid & 63, g = l >> 4, lr = l & 15;
    int chain = b * HH + h;

    __shared__ float Bs[LL][17];   // decay-folded B (f32)

    size_t row0 = (size_t)b * SS + (size_t)c * LL;
    const float* Xp = X + (row0 * HH + h) * PP;
    const float* Bp = B + (row0 * HH + h) * NN;
    const float* Ap = A + row0 * HH + h;

    // issue loads: A first (scan needs it), then B, then X (stays in flight)
    float av = Ap[(size_t)l * HH];
    int r = tid >> 2, q = tid & 3;
    float4 br = *(const float4*)(Bp + (size_t)r * (HH * NN) + q * 4);
    float xr[16];
#pragma unroll
    for (int kt = 0; kt < 2; ++kt)
#pragma unroll
        for (int e = 0; e < 8; ++e)
            xr[kt * 8 + e] = Xp[(size_t)(kt * 32 + g * 8 + e) * (HH * PP) + 16 * w + lr];

    // wave-redundant inclusive scan of A: lane holds cs[lane]
    float x = av;
#pragma unroll
    for (int d = 1; d < 64; d <<= 1) {
        float t = __shfl_up(x, d, 64);
        if (l >= d) x += t;
    }
    float alast = __shfl(x, 63, 64);

    // fold decay into B at LDS-write time: row r, weight exp(alast - cs[r])
    float wlr = __expf(alast - __shfl(x, r & 63, 64));
    Bs[r][q * 4 + 0] = br.x * wlr;
    Bs[r][q * 4 + 1] = br.y * wlr;
    Bs[r][q * 4 + 2] = br.z * wlr;
    Bs[r][q * 4 + 3] = br.w * wlr;
    __syncthreads();

    // fragments: A-op = decayed B^T (rows n=lr), B-op = X^T (cols p=16w+lr)
    bf16x8 bt[2], xf[2];
#pragma unroll
    for (int kt = 0; kt < 2; ++kt)
#pragma unroll
        for (int e = 0; e < 8; ++e) {
            int row = kt * 32 + g * 8 + e;
            bt[kt][e] = f2bf(Bs[row][lr]);
            xf[kt][e] = f2bf(xr[kt * 8 + e]);
        }
    f32x4 st = __builtin_amdgcn_mfma_f32_16x16x32_bf16(bt[0], xf[0], (f32x4)0.f, 0, 0, 0);
    st = __builtin_amdgcn_mfma_f32_16x16x32_bf16(bt[1], xf[1], st, 0, 0, 0);

    // D: lane -> S[p=16w+lr][n=4g+rr]
    float4 pv = {st[0], st[1], st[2], st[3]};
    *(float4*)(states + (size_t)(chain * CC + c) * (PP * NN) + (16 * w + lr) * NN + 4 * g) = pv;
    if (tid == 0) alast_g[chain * CC + c] = alast;
}

// ---------------------------------------------------------------------------
// K2: per chain, in-place 128-step scan: read S_c, write P_c (incoming prefix).
// ---------------------------------------------------------------------------
__global__ __launch_bounds__(256) void k2_scan(
    float* __restrict__ states, const float* __restrict__ alast_g)
{
    int chain = blockIdx.x >> 2;
    int t = ((blockIdx.x & 3) << 8) + threadIdx.x;    // 0..1023
    __shared__ float eal[CC];
    if (threadIdx.x < CC)
        eal[threadIdx.x] = __expf(alast_g[chain * CC + threadIdx.x]);
    __syncthreads();

    float* base = states + (size_t)chain * CC * (PP * NN) + t;
    float P = 0.f;
    for (int c0 = 0; c0 < CC; c0 += 8) {
        float s[8], o[8];
#pragma unroll
        for (int u = 0; u < 8; ++u) s[u] = base[(size_t)(c0 + u) * (PP * NN)];
#pragma unroll
        for (int u = 0; u < 8; ++u) { o[u] = P; P = eal[c0 + u] * P + s[u]; }
#pragma unroll
        for (int u = 0; u < 8; ++u) base[(size_t)(c0 + u) * (PP * NN)] = o[u];
    }
}

// ---------------------------------------------------------------------------
// K3: one block per chunk. Async staging: X loads in flight during
// Yoff+scores phase; converted and consumed in Ydiag phase.
// ---------------------------------------------------------------------------
__global__ __launch_bounds__(256) void k3_y(
    const float* __restrict__ X, const float* __restrict__ A,
    const float* __restrict__ Bm, const float* __restrict__ Cm,
    const float* __restrict__ pin, float* __restrict__ Y)
{
    int blk = blockIdx.x;
    int h = blk & (HH - 1);
    int c = (blk >> 5) & (CC - 1);
    int b = blk >> 12;
    int tid = threadIdx.x;
    int w = tid >> 6, l = tid & 63, g = l >> 4, lr = l & 15;
    int chain = b * HH + h;

    __shared__ short XTF[8 * 64 * 8];   // X^T B-frags (8 KB)
    __shared__ short ScF[8 * 64 * 8];   // score A-frags, wave-private (8 KB)
    __shared__ short BsF[4 * 64 * 8];   // B B-frags (4 KB)
    __shared__ short PF[4 * 64 * 8];    // P B-frags (4 KB)

    size_t row0 = (size_t)b * SS + (size_t)c * LL;
    const float* Xp = X + (row0 * HH + h) * PP;
    const float* Bp = Bm + (row0 * HH + h) * NN;
    const float* Cp = Cm + (row0 * HH + h) * NN;
    const float* Ap = A + row0 * HH + h;
    float* Yp = Y + (row0 * HH + h) * PP;

    // ---- issue loads: A, B, C, P first; X last (stays in flight) ----
    float av = Ap[(size_t)l * HH];
    int r = tid >> 2, q = tid & 3;
    float4 br = *(const float4*)(Bp + (size_t)r * (HH * NN) + q * 4);
    float4 cr0 = {0,0,0,0}, cr1 = {0,0,0,0};
    if (g < 2) {
        const float* crp = Cp + (size_t)(16 * w + lr) * (HH * NN) + g * 8;
        cr0 = *(const float4*)crp;
        cr1 = *(const float4*)(crp + 4);
    }
    float4 pinv = *(const float4*)(pin + (size_t)(chain * CC + c) * (PP * NN) + (16 * w + lr) * NN + 4 * g);
    float xr[16];
#pragma unroll
    for (int si = 0; si < 2; ++si) {
        int k0 = si * 32 + g * 8;
#pragma unroll
        for (int e = 0; e < 8; ++e)
            xr[si * 8 + e] = Xp[(size_t)(k0 + e) * (HH * PP) + 16 * w + lr];
    }

    // wave-redundant scan: lane holds cs[lane]
    float x = av;
#pragma unroll
    for (int d = 1; d < 64; d <<= 1) {
        float t = __shfl_up(x, d, 64);
        if (l >= d) x += t;
    }
    float cs_i[4], ei[4];
    int ib = 16 * w + 4 * g;
#pragma unroll
    for (int rr = 0; rr < 4; ++rr) {
        cs_i[rr] = __shfl(x, ib + rr, 64);
        ei[rr] = __expf(cs_i[rr]);
    }

    // ---- LDS staging (no X) ----
    ((bf16x8*)ScF)[tid] = (bf16x8)0;            // zero: covers j>i tiles
    ((bf16x8*)ScF)[tid + 256] = (bf16x8)0;
    if (tid < 128)                               // zero PF k>=16 half
        ((bf16x8*)PF)[(tid >> 5) * 64 + 32 + (tid & 31)] = (bf16x8)0;
    {
        int fl = (r & 15) + 16 * (q >> 1);
        int jt = r >> 4;
        bf16x4 bb = { f2bf(br.x), f2bf(br.y), f2bf(br.z), f2bf(br.w) };
        ((bf16x4*)BsF)[(jt * 64 + fl) * 2 + (q & 1)] = bb;
        int zt = tid >> 6, zu = (tid >> 1) & 31, zv = tid & 1;
        ((bf16x4*)BsF)[(zt * 64 + 32 + zu) * 2 + zv] = (bf16x4)0;
    }
    {
        float P4[4] = {pinv.x, pinv.y, pinv.z, pinv.w};
#pragma unroll
        for (int rr = 0; rr < 4; ++rr) {
            int n = 4 * g + rr;
            PF[(w * 64 + (n >> 3) * 16 + lr) * 8 + (n & 7)] = f2bf(P4[rr]);
        }
    }
    bf16x8 caw = (bf16x8)0;
    if (g < 2) {
        caw[0] = f2bf(cr0.x); caw[1] = f2bf(cr0.y);
        caw[2] = f2bf(cr0.z); caw[3] = f2bf(cr0.w);
        caw[4] = f2bf(cr1.x); caw[5] = f2bf(cr1.y);
        caw[6] = f2bf(cr1.z); caw[7] = f2bf(cr1.w);
    }
    __syncthreads();   // barrier 1: BsF/PF/ScF-zero ready; X still in flight

    // ---- phase A: Yoff + scores (no X dependence) ----
    f32x4 acc[4];
#pragma unroll
    for (int pt = 0; pt < 4; ++pt) {
        bf16x8 pfv = ((bf16x8*)PF)[pt * 64 + l];
        acc[pt] = __builtin_amdgcn_mfma_f32_16x16x32_bf16(caw, pfv, (f32x4)0.f, 0, 0, 0);
    }
#pragma unroll
    for (int pt = 0; pt < 4; ++pt)
#pragma unroll
        for (int rr = 0; rr < 4; ++rr) acc[pt][rr] *= ei[rr];

    for (int jt = 0; jt <= w; ++jt) {
        bf16x8 bw = ((bf16x8*)BsF)[jt * 64 + l];
        f32x4 sr = __builtin_amdgcn_mfma_f32_16x16x32_bf16(caw, bw, (f32x4)0.f, 0, 0, 0);
        int j = jt * 16 + lr;
        float csj = __shfl(x, j, 64);
        int kt2 = j >> 5;
        int flb = 16 * ((j >> 3) & 3);
#pragma unroll
        for (int rr = 0; rr < 4; ++rr) {
            int i15 = g * 4 + rr;
            int i = 16 * w + i15;
            float v = (j <= i) ? sr[rr] * __expf(cs_i[rr] - csj) : 0.f;
            ScF[((w * 2 + kt2) * 64 + i15 + flb) * 8 + (j & 7)] = f2bf(v);
        }
    }

    // ---- convert X (vmcnt drains here) and publish fragments ----
#pragma unroll
    for (int si = 0; si < 2; ++si) {
        bf16x8 xb;
#pragma unroll
        for (int e = 0; e < 8; ++e) xb[e] = f2bf(xr[si * 8 + e]);
        ((bf16x8*)XTF)[tid + si * 256] = xb;    // slot (si*4+w)*64+l
    }
    __syncthreads();   // barrier 2: XTF ready

    // ---- phase B: Ydiag ----
    int kts = (w >= 2) ? 2 : 1;
    for (int kt = 0; kt < kts; ++kt) {
        bf16x8 af = ((bf16x8*)ScF)[(w * 2 + kt) * 64 + l];
#pragma unroll
        for (int pt = 0; pt < 4; ++pt) {
            bf16x8 xf = ((bf16x8*)XTF)[(kt * 4 + pt) * 64 + l];
            acc[pt] = __builtin_amdgcn_mfma_f32_16x16x32_bf16(af, xf, acc[pt], 0, 0, 0);
        }
    }

    // ---- store Y: i = 16w + 4g + rr, p = 16pt + lr ----
#pragma unroll
    for (int pt = 0; pt < 4; ++pt)
#pragma unroll
        for (int rr = 0; rr < 4; ++rr)
            Yp[(size_t)(16 * w + 4 * g + rr) * (HH * PP) + pt * 16 + lr] = acc[pt][rr];
}

// ---------------------------------------------------------------------------
extern "C" void kernel_launch(void* const* d_in, const int* in_sizes, int n_in,
                              void* d_out, int out_size, void* d_ws, size_t ws_size,
                              hipStream_t stream)
{
    const float* X = (const float*)d_in[0];
    const float* A = (const float*)d_in[1];
    const float* B = (const float*)d_in[2];
    const float* C = (const float*)d_in[3];
    float* Y = (float*)d_out;

    float* states = (float*)d_ws;                              // 64 MiB
    float* alast  = states + (size_t)NCHT * (PP * NN);         // 64 KiB

    dim3 blk(256);
    k1_states<<<dim3(NCHT), blk, 0, stream>>>(X, A, B, states, alast);
    k2_scan<<<dim3(NCHAIN * 4), blk, 0, stream>>>(states, alast);
    k3_y<<<dim3(NCHT), blk, 0, stream>>>(X, A, B, C, states, Y);
}